// Round 4
// baseline (17478.407 us; speedup 1.0000x reference)
//
#include <hip/hip_runtime.h>
#include <stdint.h>
#include <math.h>

#define NVARS 1024
#define KDIM 32
#define BATCH 64
#define NIN 768
#define MAXIT 10

// ---- threefry2x32 block, exactly matching JAX (20 rounds, inject every 4) ----
__device__ __forceinline__ void tf2x32(uint32_t key0, uint32_t key1,
                                       uint32_t& x0, uint32_t& x1) {
  uint32_t ks2 = key0 ^ key1 ^ 0x1BD11BDAu;
  x0 += key0; x1 += key1;
#define TFR(r) { x0 += x1; x1 = (x1 << r) | (x1 >> (32 - r)); x1 ^= x0; }
  TFR(13) TFR(15) TFR(26) TFR(6)
  x0 += key1; x1 += ks2 + 1u;
  TFR(17) TFR(29) TFR(16) TFR(24)
  x0 += ks2;  x1 += key0 + 2u;
  TFR(13) TFR(15) TFR(26) TFR(6)
  x0 += key0; x1 += key1 + 3u;
  TFR(17) TFR(29) TFR(16) TFR(24)
  x0 += key1; x1 += ks2 + 4u;
  TFR(13) TFR(15) TFR(26) TFR(6)
  x0 += ks2;  x1 += key0 + 5u;
#undef TFR
}

// partitionable random_bits (32-bit): one block per element, counter (0, flat),
// output = x0_out ^ x1_out   [jax_threefry_partitionable=True semantics]
__device__ __forceinline__ uint32_t pbits(uint32_t k0, uint32_t k1, uint32_t flat) {
  uint32_t x0 = 0u, x1 = flat;
  tf2x32(k0, k1, x0, x1);
  return x0 ^ x1;
}

// ---- XLA f32 erf_inv (Giles polynomial), as lowered by jax.lax.erf_inv ----
__device__ __forceinline__ float erfinv_xla(float x) {
  float w = -log1pf(-x * x);
  float p;
  if (w < 5.0f) {
    w -= 2.5f;
    p = 2.81022636e-08f;
    p = fmaf(p, w, 3.43273939e-07f);
    p = fmaf(p, w, -3.5233877e-06f);
    p = fmaf(p, w, -4.39150654e-06f);
    p = fmaf(p, w, 0.00021858087f);
    p = fmaf(p, w, -0.00125372503f);
    p = fmaf(p, w, -0.00417768164f);
    p = fmaf(p, w, 0.246640727f);
    p = fmaf(p, w, 1.50140941f);
  } else {
    w = sqrtf(w) - 3.0f;
    p = -0.000200214257f;
    p = fmaf(p, w, 0.000100950558f);
    p = fmaf(p, w, 0.00134934322f);
    p = fmaf(p, w, -0.00367342844f);
    p = fmaf(p, w, 0.00573950773f);
    p = fmaf(p, w, -0.0076224613f);
    p = fmaf(p, w, 0.00943887047f);
    p = fmaf(p, w, 1.00167406f);
    p = fmaf(p, w, 2.83297682f);
  }
  return p * x;
}

// bits -> uniform(-0.99999994, 1) -> sqrt(2)*erfinv  (JAX _normal_real for f32)
__device__ __forceinline__ float bits_to_normal(uint32_t bits) {
  uint32_t fb = (bits >> 9) | 0x3F800000u;
  float f = __uint_as_float(fb) - 1.0f;          // [0,1)
  const float lo = -0.99999994f;                 // nextafter(-1,0)
  float u = fmaf(f, 2.0f, lo);                   // (hi-lo) rounds to exactly 2.0f
  u = fmaxf(lo, u);
  return 1.41421356237f * erfinv_xla(u);
}

// sum across the 32-lane half-wave group (lanes with same tid>>5), f64
__device__ __forceinline__ double red32d(double v) {
  v += __shfl_xor(v, 16);
  v += __shfl_xor(v, 8);
  v += __shfl_xor(v, 4);
  v += __shfl_xor(v, 2);
  v += __shfl_xor(v, 1);
  return v;
}

__global__ void cvtC_kernel(const float* __restrict__ C, double* __restrict__ C64) {
  int i = blockIdx.x * 256 + threadIdx.x;
  C64[i] = (double)C[i];
}

template <bool USE64>
__global__ __launch_bounds__(256) void mixnet_kernel(
    const float* __restrict__ C, const double* __restrict__ C64,
    const float* __restrict__ zin, const int* __restrict__ is_in,
    float* __restrict__ out) {
  extern __shared__ char smemraw[];
  float*  Vs    = (float*)smemraw;                       // 1024*32 f32 = 128 KB
  double* redD  = (double*)(smemraw + 131072);           // 128 f64 = 1 KB
  float*  freeS = (float*)(smemraw + 131072 + 1024);     // 1024 f32 = 4 KB

  const int tid  = threadIdx.x;
  const int b    = blockIdx.x;
  const int k    = tid & 31;   // K index
  const int rg   = tid >> 5;   // 0..7 : j-chunk id
  const int wave = tid >> 6;
  const int lane = tid & 63;

  // free flags (per batch)
  for (int i = tid; i < NVARS; i += 256) {
    float fr;
    if (i == 0) fr = 0.f;
    else if (i <= NIN) fr = (is_in[b * NIN + i - 1] == 0) ? 1.f : 0.f;
    else fr = 1.f;
    freeS[i] = fr;
  }

  // k1, k2 = jax.random.split(jax.random.key(42))  [foldlike / partitionable]
  // k1 = block((0,42),(0,0)) both words; k2 = block((0,42),(0,1))
  uint32_t a0 = 0u, a1 = 0u; tf2x32(0u, 42u, a0, a1);   // k1 = (a0, a1)
  uint32_t b0 = 0u, b1 = 1u; tf2x32(0u, 42u, b0, b1);   // k2 = (b0, b1)

  // v0: normal(k1,(64,32)) normalized per batch (f64 reduction)
  double v0kd;
  {
    uint32_t flat = (uint32_t)(b * KDIM + k);
    float raw = bits_to_normal(pbits(a0, a1, flat));
    double n2 = red32d((double)raw * (double)raw);
    v0kd = (double)raw / sqrt(n2);
  }

  const double PI_D = 3.14159265358979323846;

  // R: normal(k2,(64,1024,32)); project out v0; normalize; build V. (f64 math)
  for (int m = 0; m < NVARS / 8; ++m) {
    int n = rg + 8 * m;
    double val;
    if (n == 0) {
      val = v0kd;  // V[:,0] = v0
    } else {
      uint32_t flat = ((uint32_t)(b * NVARS + n)) * KDIM + (uint32_t)k;
      float rf = bits_to_normal(pbits(b0, b1, flat));
      double r   = (double)rf;
      double dot = red32d(r * v0kd);
      double rp  = r - dot * v0kd;
      double rn2 = red32d(rp * rp);
      double rn  = rp / sqrt(rn2);
      val = rn;                        // free / aux branch
      if (n <= NIN) {
        if (is_in[b * NIN + n - 1] > 0) {
          double zf = (double)zin[b * NIN + n - 1];
          double cc = cos(PI_D * zf);
          double ss = sin(PI_D * zf);
          val = -cc * v0kd + ss * rn;  // input branch
        }
      }
    }
    Vs[n * KDIM + k] = (float)val;
  }
  __syncthreads();

  // ---- Mixing solve: 10 sweeps, sequential coordinate descent, f64 math ----
  for (int it = 0; it < MAXIT; ++it) {
    for (int i = 1; i < NVARS; ++i) {
      if (freeS[i] == 0.f) continue;  // non-free rows are a no-op (uniform per block)
      const float* Vp = Vs + rg * 128 * KDIM + k;
      double acc0 = 0., acc1 = 0., acc2 = 0., acc3 = 0.;
      if (USE64) {
        const double* Crow = C64 + (size_t)i * NVARS + rg * 128;
#pragma unroll
        for (int jj = 0; jj < 32; ++jj) {
          acc0 = fma(Crow[jj],      (double)Vp[(jj)      * KDIM], acc0);
          acc1 = fma(Crow[jj + 32], (double)Vp[(jj + 32) * KDIM], acc1);
          acc2 = fma(Crow[jj + 64], (double)Vp[(jj + 64) * KDIM], acc2);
          acc3 = fma(Crow[jj + 96], (double)Vp[(jj + 96) * KDIM], acc3);
        }
      } else {
        const float* Crow = C + (size_t)i * NVARS + rg * 128;
#pragma unroll
        for (int jj = 0; jj < 32; ++jj) {
          acc0 = fma((double)Crow[jj],      (double)Vp[(jj)      * KDIM], acc0);
          acc1 = fma((double)Crow[jj + 32], (double)Vp[(jj + 32) * KDIM], acc1);
          acc2 = fma((double)Crow[jj + 64], (double)Vp[(jj + 64) * KDIM], acc2);
          acc3 = fma((double)Crow[jj + 96], (double)Vp[(jj + 96) * KDIM], acc3);
        }
      }
      double partial = (acc0 + acc1) + (acc2 + acc3);
      partial += __shfl_down(partial, 32);   // combine the wave's two chunks
      if (lane < 32) redD[wave * 32 + k] = partial;
      __syncthreads();
      if (tid < 32) {
        double g  = redD[k] + redD[32 + k] + redD[64 + k] + redD[96 + k];
        double sq = red32d(g * g);
        double gn = fmax(sqrt(sq), 1e-12);
        Vs[i * KDIM + k] = (float)(-g / gn);
      }
      __syncthreads();
    }
  }

  // ---- epilogue: z_out = free ? arccos(clip(-V.v0))/pi : z  (f64) ----
  for (int m = 0; m < NVARS / 8; ++m) {
    int n = rg + 8 * m;
    if (n >= 1 && n <= NIN) {
      float zo;
      if (freeS[n] != 0.f) {
        double dot = red32d((double)Vs[n * KDIM + k] * v0kd);
        double ca  = fmin(fmax(-dot, -1.0 + 1e-7), 1.0 - 1e-7);
        zo = (float)(acos(ca) / PI_D);
      } else {
        zo = zin[b * NIN + n - 1];
      }
      if (k == 0) out[b * NIN + n - 1] = zo;
    }
  }
}

extern "C" void kernel_launch(void* const* d_in, const int* in_sizes, int n_in,
                              void* d_out, int out_size, void* d_ws, size_t ws_size,
                              hipStream_t stream) {
  const float* C        = (const float*)d_in[0];
  const float* z        = (const float*)d_in[1];
  const int*   is_input = (const int*)d_in[2];
  float*       out      = (float*)d_out;

  size_t smem = 131072 + 1024 + 4096;  // 133 KB
  const size_t need64 = (size_t)NVARS * NVARS * sizeof(double);  // 8 MB
  bool use64 = (ws_size >= need64) && (d_ws != nullptr);

  (void)hipFuncSetAttribute((const void*)mixnet_kernel<true>,
                            hipFuncAttributeMaxDynamicSharedMemorySize, (int)smem);
  (void)hipFuncSetAttribute((const void*)mixnet_kernel<false>,
                            hipFuncAttributeMaxDynamicSharedMemorySize, (int)smem);

  if (use64) {
    double* C64 = (double*)d_ws;
    cvtC_kernel<<<NVARS * NVARS / 256, 256, 0, stream>>>(C, C64);
    mixnet_kernel<true><<<BATCH, 256, smem, stream>>>(C, C64, z, is_input, out);
  } else {
    mixnet_kernel<false><<<BATCH, 256, smem, stream>>>(C, nullptr, z, is_input, out);
  }
}

// Round 5
// 17010.512 us; speedup vs baseline: 1.0275x; 1.0275x over previous
//
#include <hip/hip_runtime.h>
#include <stdint.h>
#include <math.h>

#define NVARS 1024
#define KDIM 32
#define BATCH 64
#define NIN 768
#define MAXIT 10
#define BLK 32

// LDS layout (bytes):
//   Vs    @ 0       float [1024][32]  128 KB
//   Pb    @ 131072  double[32][32]      8 KB
//   CsT   @ 139264  float [32][32]      4 KB   CsT[m][l'] = C[i_l'][i_m]
//   flist @ 143360  int   [1024]        4 KB
//   wcnt  @ 147456  int   [16]
//   nfs   @ 147520  int   [1]
#define SMEM_BYTES 147584

// ---- threefry2x32 block, exactly matching JAX (20 rounds, inject every 4) ----
__device__ __forceinline__ void tf2x32(uint32_t key0, uint32_t key1,
                                       uint32_t& x0, uint32_t& x1) {
  uint32_t ks2 = key0 ^ key1 ^ 0x1BD11BDAu;
  x0 += key0; x1 += key1;
#define TFR(r) { x0 += x1; x1 = (x1 << r) | (x1 >> (32 - r)); x1 ^= x0; }
  TFR(13) TFR(15) TFR(26) TFR(6)
  x0 += key1; x1 += ks2 + 1u;
  TFR(17) TFR(29) TFR(16) TFR(24)
  x0 += ks2;  x1 += key0 + 2u;
  TFR(13) TFR(15) TFR(26) TFR(6)
  x0 += key0; x1 += key1 + 3u;
  TFR(17) TFR(29) TFR(16) TFR(24)
  x0 += key1; x1 += ks2 + 4u;
  TFR(13) TFR(15) TFR(26) TFR(6)
  x0 += ks2;  x1 += key0 + 5u;
#undef TFR
}

// partitionable random_bits (32-bit): counter (0, flat), out = x0 ^ x1
__device__ __forceinline__ uint32_t pbits(uint32_t k0, uint32_t k1, uint32_t flat) {
  uint32_t x0 = 0u, x1 = flat;
  tf2x32(k0, k1, x0, x1);
  return x0 ^ x1;
}

// ---- XLA f32 erf_inv (Giles polynomial) ----
__device__ __forceinline__ float erfinv_xla(float x) {
  float w = -log1pf(-x * x);
  float p;
  if (w < 5.0f) {
    w -= 2.5f;
    p = 2.81022636e-08f;
    p = fmaf(p, w, 3.43273939e-07f);
    p = fmaf(p, w, -3.5233877e-06f);
    p = fmaf(p, w, -4.39150654e-06f);
    p = fmaf(p, w, 0.00021858087f);
    p = fmaf(p, w, -0.00125372503f);
    p = fmaf(p, w, -0.00417768164f);
    p = fmaf(p, w, 0.246640727f);
    p = fmaf(p, w, 1.50140941f);
  } else {
    w = sqrtf(w) - 3.0f;
    p = -0.000200214257f;
    p = fmaf(p, w, 0.000100950558f);
    p = fmaf(p, w, 0.00134934322f);
    p = fmaf(p, w, -0.00367342844f);
    p = fmaf(p, w, 0.00573950773f);
    p = fmaf(p, w, -0.0076224613f);
    p = fmaf(p, w, 0.00943887047f);
    p = fmaf(p, w, 1.00167406f);
    p = fmaf(p, w, 2.83297682f);
  }
  return p * x;
}

__device__ __forceinline__ float bits_to_normal(uint32_t bits) {
  uint32_t fb = (bits >> 9) | 0x3F800000u;
  float f = __uint_as_float(fb) - 1.0f;
  const float lo = -0.99999994f;
  float u = fmaf(f, 2.0f, lo);
  u = fmaxf(lo, u);
  return 1.41421356237f * erfinv_xla(u);
}

// sum across the 32-lane group (lanes sharing tid>>5), f64
__device__ __forceinline__ double red32d(double v) {
  v += __shfl_xor(v, 16);
  v += __shfl_xor(v, 8);
  v += __shfl_xor(v, 4);
  v += __shfl_xor(v, 2);
  v += __shfl_xor(v, 1);
  return v;
}

__global__ void cvtC_kernel(const float* __restrict__ C, double* __restrict__ C64) {
  int i = blockIdx.x * 256 + threadIdx.x;
  C64[i] = (double)C[i];
}

__global__ __launch_bounds__(1024) void mixnet_kernel(
    const float* __restrict__ C32, const double* __restrict__ C64,
    const float* __restrict__ zin, const int* __restrict__ is_in,
    float* __restrict__ out) {
  extern __shared__ char smemraw[];
  float*  Vs    = (float*)smemraw;
  double* Pb    = (double*)(smemraw + 131072);
  float*  CsT   = (float*)(smemraw + 139264);
  int*    flist = (int*)(smemraw + 143360);
  int*    wcnt  = (int*)(smemraw + 147456);
  int*    nfs   = (int*)(smemraw + 147520);

  const int tid  = threadIdx.x;
  const int b    = blockIdx.x;
  const int k    = tid & 31;   // K index
  const int rown = tid >> 5;   // 0..31
  const int wave = tid >> 6;   // 0..15
  const int lane = tid & 63;

  // ---- free flags -> compacted free-row list (ballot scan) ----
  bool myfree;
  {
    int row = tid;  // 0..1023
    if (row == 0) myfree = false;
    else if (row <= NIN) myfree = (is_in[b * NIN + row - 1] == 0);
    else myfree = true;
    unsigned long long mask = __ballot(myfree);
    if (lane == 0) wcnt[wave] = __popcll(mask);
    __syncthreads();
    if (tid == 0) {
      int s = 0;
      for (int w = 0; w < 16; ++w) { int c = wcnt[w]; wcnt[w] = s; s += c; }
      nfs[0] = s;
    }
    __syncthreads();
    if (myfree) {
      int pos = wcnt[wave] + __popcll(mask & ((1ull << lane) - 1ull));
      flist[pos] = row;
    }
  }

  // k1, k2 = jax.random.split(jax.random.key(42))  [partitionable]
  uint32_t a0 = 0u, a1 = 0u; tf2x32(0u, 42u, a0, a1);
  uint32_t b0 = 0u, b1 = 1u; tf2x32(0u, 42u, b0, b1);

  // v0 (f64 normalize)
  double v0kd;
  {
    float raw = bits_to_normal(pbits(a0, a1, (uint32_t)(b * KDIM + k)));
    double n2 = red32d((double)raw * (double)raw);
    v0kd = (double)raw / sqrt(n2);
  }

  const double PI_D = 3.14159265358979323846;

  // Build V (f64 math, f32 storage)
  for (int m = 0; m < 32; ++m) {
    int n = m * 32 + rown;
    double val;
    if (n == 0) {
      val = v0kd;
    } else {
      uint32_t flat = ((uint32_t)(b * NVARS + n)) * KDIM + (uint32_t)k;
      float rf = bits_to_normal(pbits(b0, b1, flat));
      double r   = (double)rf;
      double dot = red32d(r * v0kd);
      double rp  = r - dot * v0kd;
      double rn2 = red32d(rp * rp);
      double rn  = rp / sqrt(rn2);
      val = rn;
      if (n <= NIN) {
        if (is_in[b * NIN + n - 1] > 0) {
          double zf = (double)zin[b * NIN + n - 1];
          val = -cos(PI_D * zf) * v0kd + sin(PI_D * zf) * rn;
        }
      }
    }
    Vs[n * KDIM + k] = (float)val;
  }
  __syncthreads();

  const int nf = nfs[0];

  // ---- blocked Gauss-Seidel: 10 sweeps ----
  for (int it = 0; it < MAXIT; ++it) {
    for (int blk0 = 0; blk0 < nf; blk0 += BLK) {
      const int L = min(BLK, nf - blk0);

      // stage 32x32 coupling block: CsT[m][lp] = C[i_lp][i_m]
      {
        int m = k, lp = rown;
        if (m < L && lp < L)
          CsT[m * 32 + lp] =
              C32[(size_t)flist[blk0 + lp] * NVARS + flist[blk0 + m]];
      }

      // phase A: P[l][k] = C64[i_l] . V   (thread owns full dot, f64)
      if (rown < L) {
        const double* Crow = C64 + (size_t)flist[blk0 + rown] * NVARS;
        const float*  Vp   = Vs + k;
        double ac0 = 0., ac1 = 0., ac2 = 0., ac3 = 0.;
#pragma unroll 8
        for (int j = 0; j < NVARS; j += 4) {
          ac0 = fma(Crow[j],     (double)Vp[(j)     * 32], ac0);
          ac1 = fma(Crow[j + 1], (double)Vp[(j + 1) * 32], ac1);
          ac2 = fma(Crow[j + 2], (double)Vp[(j + 2) * 32], ac2);
          ac3 = fma(Crow[j + 3], (double)Vp[(j + 3) * 32], ac3);
        }
        Pb[rown * 32 + k] = (ac0 + ac1) + (ac2 + ac3);
      }
      __syncthreads();

      // phase B: sequential 32 rows, wave 0 only, register-resident
      if (wave == 0) {
        const int s  = lane >> 5;   // laneset: rows [16s, 16s+16)
        const int kk = lane & 31;
        double pr[16]; float vr[16]; int rowi[16];
#pragma unroll
        for (int q = 0; q < 16; ++q) {
          int l2 = s * 16 + q;
          rowi[q] = 0; pr[q] = 0.; vr[q] = 0.f;
          if (l2 < L) {
            rowi[q] = flist[blk0 + l2];
            pr[q]   = Pb[l2 * 32 + kk];
            vr[q]   = Vs[rowi[q] * 32 + kk];
          }
        }
#pragma unroll
        for (int l = 0; l < BLK; ++l) {
          if (l >= L) break;
          // coefficient column for source row l (lane-uniform broadcast reads)
          float cf[16];
#pragma unroll
          for (int q2 = 0; q2 < 16; ++q2) cf[q2] = CsT[l * 32 + s * 16 + q2];

          const bool owner = ((l >> 4) == s);
          const int  q = l & 15;
          double dv = 0.0;
          if (owner) {
            double g  = pr[q];
            double ss = red32d(g * g);
            double gn = fmax(sqrt(ss), 1e-12);
            float vnf = (float)(-g / gn);
            dv = (double)vnf - (double)vr[q];
            vr[q] = vnf;
            Vs[rowi[q] * 32 + kk] = vnf;
          }
          double dvo = __shfl_xor(dv, 32);
          double dvl = owner ? dv : dvo;
#pragma unroll
          for (int q2 = 0; q2 < 16; ++q2) {
            int l2 = s * 16 + q2;
            if (l2 > l && l2 < L) pr[q2] = fma((double)cf[q2], dvl, pr[q2]);
          }
        }
      }
      __syncthreads();
    }
  }

  // ---- epilogue: z_out = free ? arccos(clip(-V.v0))/pi : z  (f64) ----
  for (int m = 0; m < 32; ++m) {
    int n = m * 32 + rown;
    if (n >= 1 && n <= NIN) {
      bool fr = (is_in[b * NIN + n - 1] == 0);
      float zo;
      if (fr) {
        double dot = red32d((double)Vs[n * KDIM + k] * v0kd);
        double ca  = fmin(fmax(-dot, -1.0 + 1e-7), 1.0 - 1e-7);
        zo = (float)(acos(ca) / PI_D);
      } else {
        zo = zin[b * NIN + n - 1];
      }
      if (k == 0) out[b * NIN + n - 1] = zo;
    }
  }
}

extern "C" void kernel_launch(void* const* d_in, const int* in_sizes, int n_in,
                              void* d_out, int out_size, void* d_ws, size_t ws_size,
                              hipStream_t stream) {
  const float* C        = (const float*)d_in[0];
  const float* z        = (const float*)d_in[1];
  const int*   is_input = (const int*)d_in[2];
  float*       out      = (float*)d_out;

  double* C64 = (double*)d_ws;  // 8 MB, validated available in R4

  (void)hipFuncSetAttribute((const void*)mixnet_kernel,
                            hipFuncAttributeMaxDynamicSharedMemorySize,
                            SMEM_BYTES);

  cvtC_kernel<<<NVARS * NVARS / 256, 256, 0, stream>>>(C, C64);
  mixnet_kernel<<<BATCH, 1024, SMEM_BYTES, stream>>>(C, C64, z, is_input, out);
}